// Round 4
// baseline (62.261 us; speedup 1.0000x reference)
//
#include <hip/hip_runtime.h>
#include <hip/hip_bf16.h>

#define DIN  1024
#define DOUT 1024
#define MROWS 8192   // B*S = 4*2048

#define BM 256
#define BN 128
#define BK 64
#define NKT (DIN / BK)   // 16 K-tiles

typedef __attribute__((ext_vector_type(8))) short short8;
typedef __attribute__((ext_vector_type(4))) float f32x4;

__device__ __forceinline__ ushort f2bf(float f) {
    union { float f; unsigned u; } x; x.f = f;
    unsigned u = x.u + 0x7fffu + ((x.u >> 16) & 1u);  // RNE
    return (ushort)(u >> 16);
}

// ---------- prep: Wv [K][N] f32 -> WvT [N][K] bf16 (tiled transpose, ~6MB) ----------
__global__ void prep_wt(const float* __restrict__ W, ushort* __restrict__ Wt) {
    __shared__ float tile[32][33];
    const int t  = blockIdx.x;
    const int bx = (t & 31) * 32;      // n base
    const int by = (t >> 5) * 32;      // k base
    const int tx = threadIdx.x & 31;
    const int ty = threadIdx.x >> 5;   // 0..7
#pragma unroll
    for (int i = 0; i < 32; i += 8)
        tile[ty + i][tx] = W[(size_t)(by + ty + i) * DOUT + (bx + tx)];
    __syncthreads();
#pragma unroll
    for (int i = 0; i < 32; i += 8)
        Wt[(size_t)(bx + ty + i) * DIN + (by + tx)] = f2bf(tile[tx][ty + i]);
}

// ---------- fused GEMM: C[M][N] = cvt_bf16(X)[M][K] @ WvT[N][K]^T + bias ----------
// A is reg-staged straight from f32 X (cvt in-register, swizzled ds_write) —
// the X->bf16 prep pass is GONE. B is DMA-staged (global_load_lds w16) with
// source-side XOR swizzle. T14 split: A loads for t+1 issue before tile t's
// MFMA cluster; cvt+ds_write land after it. Double-buffered, 1 barrier/tile.
__global__ __launch_bounds__(512, 2) void gemm_fused(
    const float*  __restrict__ X,     // [8192][1024] f32
    const ushort* __restrict__ Wt,    // [1024 n][1024 k] bf16
    const float*  __restrict__ bias,  // [1024]
    float* __restrict__ out)          // [8192][1024] f32
{
    __shared__ ushort As[2][BM * BK];   // 2 x 32 KiB
    __shared__ ushort Bs[2][BN * BK];   // 2 x 16 KiB   (96 KiB total)

    const int tid  = threadIdx.x;
    const int lane = tid & 63;
    const int wid  = tid >> 6;     // 0..7
    const int wr   = wid >> 1;     // 0..3  (wave M slab, 64 rows)
    const int wc   = wid & 1;      // 0..1  (wave N slab, 64 cols)

    // XCD-aware bijective swizzle: 256 blocks = 8 XCDs x 32.
    const int bid = blockIdx.x;
    const int swz = (bid & 7) * 32 + (bid >> 3);
    const int bm = (swz >> 3) * BM;
    const int bn = (swz & 7) * BN;

    // ---- A reg-staging: thread t owns row (t>>1), k-half (t&1) of the tile ----
    const int ar_ = tid >> 1;          // 0..255
    const int ah_ = tid & 1;           // 0..1 -> k offset 0/32
    const float* aSrc = X + (size_t)(bm + ar_) * DIN + ah_ * 32;

    float4 areg[8];                    // 32 f32 = half a row of the A tile
    auto loadA = [&](int kt) {
        const float4* p = (const float4*)(aSrc + kt * BK);
#pragma unroll
        for (int i = 0; i < 8; ++i) areg[i] = p[i];
    };
    // cvt + swizzled write: slot s (16B) of row r goes to s ^ (r&7)
    auto writeA = [&](int b) {
        ushort* row = &As[b][ar_ * BK];
#pragma unroll
        for (int w = 0; w < 4; ++w) {
            const float4 a0 = areg[w * 2], a1 = areg[w * 2 + 1];
            short8 v;
            v[0] = f2bf(a0.x); v[1] = f2bf(a0.y); v[2] = f2bf(a0.z); v[3] = f2bf(a0.w);
            v[4] = f2bf(a1.x); v[5] = f2bf(a1.y); v[6] = f2bf(a1.z); v[7] = f2bf(a1.w);
            const int slot = (ah_ * 4 + w) ^ (ar_ & 7);
            *(short8*)(row + slot * 8) = v;
        }
    };

    // ---- B DMA staging: linear LDS dest, XOR-swizzled global source ----
    auto dmaB = [&](int b, int kt) {
#pragma unroll
        for (int j = 0; j < 2; ++j) {
            const int c  = j * 512 + tid;      // chunk 0..1023
            const int rl = c >> 3;             // row 0..127
            const int sl = (c & 7) ^ (rl & 7); // swizzled source slot
            __builtin_amdgcn_global_load_lds(
                (const __attribute__((address_space(1))) void*)(Wt + (size_t)(bn + rl) * DIN + kt * BK + sl * 8),
                (__attribute__((address_space(3))) void*)(&Bs[b][(j * 512 + wid * 64) * 8]),
                16, 0, 0);
        }
    };

    f32x4 acc[4][4];
#pragma unroll
    for (int i = 0; i < 4; ++i)
#pragma unroll
        for (int j = 0; j < 4; ++j)
            acc[i][j] = (f32x4){0.f, 0.f, 0.f, 0.f};

    const int am  = wr * 64 + (lane & 15);
    const int bnr = wc * 64 + (lane & 15);
    auto fragRead = [&](int b, int ks, short8* af, short8* bfr) {
        const int sc = ((ks * 4 + (lane >> 4)) ^ (lane & 7)) * 8;
#pragma unroll
        for (int i = 0; i < 4; ++i)
            af[i] = *(const short8*)(&As[b][(am + i * 16) * BK + sc]);
#pragma unroll
        for (int j = 0; j < 4; ++j)
            bfr[j] = *(const short8*)(&Bs[b][(bnr + j * 16) * BK + sc]);
    };
    auto mfmaCluster = [&](short8 af[2][4], short8 bfr[2][4]) {
        __builtin_amdgcn_s_setprio(1);
#pragma unroll
        for (int ks = 0; ks < 2; ++ks)
#pragma unroll
            for (int i = 0; i < 4; ++i)
#pragma unroll
                for (int j = 0; j < 4; ++j)
                    acc[i][j] = __builtin_amdgcn_mfma_f32_16x16x32_bf16(af[ks][i], bfr[ks][j], acc[i][j], 0, 0, 0);
        __builtin_amdgcn_s_setprio(0);
    };

    // ---- prologue: stage tile 0 ----
    loadA(0);
    dmaB(0, 0);
    writeA(0);
    asm volatile("s_waitcnt vmcnt(0) lgkmcnt(0)" ::: "memory");
    __builtin_amdgcn_s_barrier();

    // ---- main loop: compute tile t, stage tile t+1 ----
    int buf = 0;
    for (int t = 0; t < NKT - 1; ++t) {
        loadA(t + 1);                       // f32 prefetch (T14 issue-early)
        dmaB(buf ^ 1, t + 1);
        __builtin_amdgcn_sched_barrier(0);  // pin stage-issue before compute
        short8 af[2][4], bfr[2][4];
        fragRead(buf, 0, af[0], bfr[0]);
        fragRead(buf, 1, af[1], bfr[1]);
        mfmaCluster(af, bfr);
        writeA(buf ^ 1);                    // T14 write-late (compiler waits A loads)
        asm volatile("s_waitcnt vmcnt(0) lgkmcnt(0)" ::: "memory");
        __builtin_amdgcn_sched_barrier(0);
        __builtin_amdgcn_s_barrier();
        buf ^= 1;
    }
    // tail: tile NKT-1
    {
        short8 af[2][4], bfr[2][4];
        fragRead(buf, 0, af[0], bfr[0]);
        fragRead(buf, 1, af[1], bfr[1]);
        mfmaCluster(af, bfr);
    }

    // ---- epilogue: bias + store. C/D: col = lane&15, row = (lane>>4)*4 + r ----
    const int crow = bm + wr * 64 + (lane >> 4) * 4;
    const int ccol = bn + wc * 64 + (lane & 15);
#pragma unroll
    for (int j = 0; j < 4; ++j) {
        const int col = ccol + j * 16;
        const float bval = bias[col];
#pragma unroll
        for (int i = 0; i < 4; ++i) {
#pragma unroll
            for (int r = 0; r < 4; ++r)
                out[(size_t)(crow + i * 16 + r) * DOUT + col] = acc[i][j][r] + bval;
        }
    }
}

// ---------- fallback (only if workspace too small): naive f32 ----------
__global__ void gemm_naive(const float* __restrict__ X, const float* __restrict__ W,
                           const float* __restrict__ b, float* __restrict__ out) {
    int n = blockIdx.x * blockDim.x + threadIdx.x;
    int m = blockIdx.y;
    float acc = b[n];
    for (int k = 0; k < DIN; ++k)
        acc += X[(size_t)m * DIN + k] * W[(size_t)k * DOUT + n];
    out[(size_t)m * DOUT + n] = acc;
}

extern "C" void kernel_launch(void* const* d_in, const int* in_sizes, int n_in,
                              void* d_out, int out_size, void* d_ws, size_t ws_size,
                              hipStream_t stream) {
    // setup_inputs order: X, Wq, bq, Wk, bk, Wv, bv
    const float* X  = (const float*)d_in[0];
    const float* Wv = (const float*)d_in[5];
    const float* bv = (const float*)d_in[6];
    float* out = (float*)d_out;

    const size_t wt_elems = (size_t)DOUT * DIN;
    if (ws_size < wt_elems * sizeof(ushort)) {
        dim3 g(DOUT / 256, MROWS);
        gemm_naive<<<g, 256, 0, stream>>>(X, Wv, bv, out);
        return;
    }

    ushort* Wt = (ushort*)d_ws;
    prep_wt<<<1024, 256, 0, stream>>>(Wv, Wt);
    gemm_fused<<<256, 512, 0, stream>>>(X, Wt, bv, out);
}

// Round 5
// 59.429 us; speedup vs baseline: 1.0477x; 1.0477x over previous
//
#include <hip/hip_runtime.h>
#include <hip/hip_bf16.h>

#define DIN  1024
#define DOUT 1024
#define MROWS 8192   // B*S = 4*2048

#define BM 256
#define BN 128
#define BK 64
#define NKT (DIN / BK)   // 16 K-tiles

typedef __attribute__((ext_vector_type(8))) short short8;
typedef __attribute__((ext_vector_type(4))) float f32x4;

__device__ __forceinline__ ushort f2bf(float f) {
    union { float f; unsigned u; } x; x.f = f;
    unsigned u = x.u + 0x7fffu + ((x.u >> 16) & 1u);  // RNE
    return (ushort)(u >> 16);
}

// ---------- pass 1 (fused): X f32->bf16 cvt  +  Wv [K][N] -> WvT [N][K] bf16 ----------
__global__ void prep_kernel(const float* __restrict__ X, ushort* __restrict__ Xb,
                            const float* __restrict__ W, ushort* __restrict__ Wt) {
    __shared__ float tile[32][33];
    const int b = blockIdx.x;
    if (b < 2048) {
        const float4* X4 = (const float4*)X;
        ushort4* O4 = (ushort4*)Xb;
        const int n4 = MROWS * DIN / 4;
        for (int idx = b * 256 + threadIdx.x; idx < n4; idx += 2048 * 256) {
            float4 v = X4[idx];
            ushort4 o;
            o.x = f2bf(v.x); o.y = f2bf(v.y); o.z = f2bf(v.z); o.w = f2bf(v.w);
            O4[idx] = o;
        }
    } else {
        const int t = b - 2048;            // 0..1023
        const int bx = (t & 31) * 32;      // n base
        const int by = (t >> 5) * 32;      // k base
        const int tx = threadIdx.x & 31;
        const int ty = threadIdx.x >> 5;   // 0..7
#pragma unroll
        for (int i = 0; i < 32; i += 8)
            tile[ty + i][tx] = W[(size_t)(by + ty + i) * DOUT + (bx + tx)];
        __syncthreads();
#pragma unroll
        for (int i = 0; i < 32; i += 8)
            Wt[(size_t)(bx + ty + i) * DIN + (by + tx)] = f2bf(tile[tx][ty + i]);
    }
}

// ---------- pass 2: C[M][N] = Xb[M][K] @ WvT[N][K]^T + bias ----------
// R2 structure (proven 27.5us GEMM) with ONE change: B fragments come from
// global (L2-resident Wt, 2MB) straight into double-buffered registers,
// prefetched one tile ahead. LDS holds A only (3-deep, 96KB). This halves
// LDS read instrs/tile (the former pole: 1540 cyc LDS vs 1242 MFMA).
__global__ __launch_bounds__(512, 2) void gemm_bias(
    const ushort* __restrict__ Xb,    // [8192][1024] bf16
    const ushort* __restrict__ Wt,    // [1024 n][1024 k] bf16
    const float* __restrict__ bias,   // [1024]
    float* __restrict__ out)          // [8192][1024] f32
{
    __shared__ ushort As[3][BM * BK];   // 3 x 32 KiB = 96 KiB

    const int tid  = threadIdx.x;
    const int lane = tid & 63;
    const int wid  = tid >> 6;     // 0..7
    const int wr   = wid >> 1;     // 0..3  (wave M slab, 64 rows)
    const int wc   = wid & 1;      // 0..1  (wave N slab, 64 cols)

    // XCD-aware bijective swizzle: 256 blocks = 8 XCDs x 32.
    const int bid = blockIdx.x;
    const int swz = (bid & 7) * 32 + (bid >> 3);
    const int bm = (swz >> 3) * BM;
    const int bn = (swz & 7) * BN;

    // A staging half h of K-tile kt into buffer b: 2 gload_lds w16 per thread.
    // LDS dest LINEAR; T2 swizzle via XOR-permuted global source (rule #21).
    auto stageA = [&](int b, int kt, int h) {
#pragma unroll
        for (int j = 0; j < 2; ++j) {
            const int c   = j * 512 + tid;      // chunk id within half (0..1023)
            const int rl  = c >> 3;             // row within half (0..127)
            const int scc = (c & 7) ^ (rl & 7); // swizzled source column chunk
            __builtin_amdgcn_global_load_lds(
                (const __attribute__((address_space(1))) void*)(Xb + (size_t)(bm + h * 128 + rl) * DIN + kt * BK + scc * 8),
                (__attribute__((address_space(3))) void*)(&As[b][h * 8192 + (j * 512 + wid * 64) * 8]),
                16, 0, 0);
        }
    };

    // B fragment loads: global -> regs. Frag (ks,j): row = wave n-slab + j*16 +
    // (lane&15); k = kt*64 + ks*32 + (lane>>4)*8. Lanes {r,r+16,r+32,r+48}
    // cover 64B contiguous per row -> decent L2 transactions.
    const ushort* bBase = Wt + (size_t)(bn + wc * 64 + (lane & 15)) * DIN + (lane >> 4) * 8;
    auto loadB = [&](short8 (&dst)[2][4], int kt) {
#pragma unroll
        for (int ks = 0; ks < 2; ++ks)
#pragma unroll
            for (int j = 0; j < 4; ++j)
                dst[ks][j] = *(const short8*)(bBase + (size_t)j * 16 * DIN + kt * BK + ks * 32);
    };

    f32x4 acc[4][4];
#pragma unroll
    for (int i = 0; i < 4; ++i)
#pragma unroll
        for (int j = 0; j < 4; ++j)
            acc[i][j] = (f32x4){0.f, 0.f, 0.f, 0.f};

    const int am = wr * 64 + (lane & 15);

    // One phase (= one k-half ks): 4 A-frag ds_reads + optional stage/loadB,
    // pre-MFMA barrier + lgkmcnt(0) + 16 MFMA, counted vmcnt, end barrier.
    // wait: -1 none, else "s_waitcnt vmcnt(wait)".
    auto phase = [&](int buf, int ks, const short8 (&bcur)[2][4],
                     bool doStage, int sbuf, int skt, int wait, bool endBar) {
        short8 af[4];
        const int sc = ((ks * 4 + (lane >> 4)) ^ (lane & 7)) * 8;
#pragma unroll
        for (int i = 0; i < 4; ++i)
            af[i] = *(const short8*)(&As[buf][(am + i * 16) * BK + sc]);
        if (doStage) stageA(sbuf, skt, ks);
        __builtin_amdgcn_s_barrier();
        asm volatile("s_waitcnt lgkmcnt(0)" ::: "memory");
        __builtin_amdgcn_sched_barrier(0);
        __builtin_amdgcn_s_setprio(1);
        if (ks == 0) {
#pragma unroll
            for (int i = 0; i < 4; ++i)
#pragma unroll
                for (int j = 0; j < 4; ++j)
                    acc[i][j] = __builtin_amdgcn_mfma_f32_16x16x32_bf16(af[i], bcur[0][j], acc[i][j], 0, 0, 0);
        } else {
#pragma unroll
            for (int i = 0; i < 4; ++i)
#pragma unroll
                for (int j = 0; j < 4; ++j)
                    acc[i][j] = __builtin_amdgcn_mfma_f32_16x16x32_bf16(af[i], bcur[1][j], acc[i][j], 0, 0, 0);
        }
        __builtin_amdgcn_s_setprio(0);
        if (wait == 12)     asm volatile("s_waitcnt vmcnt(12)" ::: "memory");
        else if (wait == 8) asm volatile("s_waitcnt vmcnt(8)"  ::: "memory");
        else if (wait == 0) asm volatile("s_waitcnt vmcnt(0)"  ::: "memory");
        if (endBar) __builtin_amdgcn_s_barrier();
    };

    short8 bA[2][4], bB[2][4];

    // ---- prologue: A(0) [4], B(0)->bA [8], A(1) [4]; need A(0)+B(0) done.
    // Queue: [A0:4, B0:8, A1:4] -> allow A1 in flight: the bA use in tile 0's
    // MFMA gets a compiler wait; our vmcnt(12) guarantees A(0) landed.
    stageA(0, 0, 0); stageA(0, 0, 1);
    loadB(bA, 0);
    stageA(1, 1, 0); stageA(1, 1, 1);
    asm volatile("s_waitcnt vmcnt(12)" ::: "memory");   // A(0) done; B0+A1 in flight
    __builtin_amdgcn_s_barrier();

    // Tile body: loadB(t+1) in phase 0; stage A(t+2) split across phases;
    // end-of-tile vmcnt(12) = B(t+1):8 + A(t+2):4 outstanding => A(t+1) landed.
    auto tileBody = [&](int t, const short8 (&cur)[2][4], short8 (&nxt)[2][4],
                        bool doLoadB, bool doStage, int wait, bool last) {
        const int buf = t % 3;
        if (doLoadB) loadB(nxt, t + 1);
        phase(buf, 0, cur, doStage, (t + 2) % 3, t + 2, -1, true);
        phase(buf, 1, cur, doStage, (t + 2) % 3, t + 2, wait, !last);
    };

    for (int tt = 0; tt < NKT - 2; tt += 2) {        // 0..13, unrolled x2 (rule #20)
        tileBody(tt,     bA, bB, true, true, 12, false);
        tileBody(tt + 1, bB, bA, true, true, 12, false);
    }
    tileBody(NKT - 2, bA, bB, true,  false, 8, false);   // t=14: B(15); A(15) landed
    tileBody(NKT - 1, bB, bA, false, false, -1, true);   // t=15: tail

    // ---- epilogue: bias + store. C/D: col = lane&15, row = (lane>>4)*4 + r ----
    const int crow = bm + wr * 64 + (lane >> 4) * 4;
    const int ccol = bn + wc * 64 + (lane & 15);
#pragma unroll
    for (int j = 0; j < 4; ++j) {
        const int col = ccol + j * 16;
        const float bval = bias[col];
#pragma unroll
        for (int i = 0; i < 4; ++i) {
#pragma unroll
            for (int r = 0; r < 4; ++r)
                out[(size_t)(crow + i * 16 + r) * DOUT + col] = acc[i][j][r] + bval;
        }
    }
}

// ---------- fallback (only if workspace too small): naive f32 ----------
__global__ void gemm_naive(const float* __restrict__ X, const float* __restrict__ W,
                           const float* __restrict__ b, float* __restrict__ out) {
    int n = blockIdx.x * blockDim.x + threadIdx.x;
    int m = blockIdx.y;
    float acc = b[n];
    for (int k = 0; k < DIN; ++k)
        acc += X[(size_t)m * DIN + k] * W[(size_t)k * DOUT + n];
    out[(size_t)m * DOUT + n] = acc;
}

extern "C" void kernel_launch(void* const* d_in, const int* in_sizes, int n_in,
                              void* d_out, int out_size, void* d_ws, size_t ws_size,
                              hipStream_t stream) {
    // setup_inputs order: X, Wq, bq, Wk, bk, Wv, bv
    const float* X  = (const float*)d_in[0];
    const float* Wv = (const float*)d_in[5];
    const float* bv = (const float*)d_in[6];
    float* out = (float*)d_out;

    const size_t xb_elems = (size_t)MROWS * DIN;
    const size_t wt_elems = (size_t)DOUT * DIN;
    const size_t needed = (xb_elems + wt_elems) * sizeof(ushort);

    if (ws_size < needed) {
        dim3 g(DOUT / 256, MROWS);
        gemm_naive<<<g, 256, 0, stream>>>(X, Wv, bv, out);
        return;
    }

    ushort* Xb = (ushort*)d_ws;
    ushort* Wt = Xb + xb_elems;

    prep_kernel<<<2048 + 1024, 256, 0, stream>>>(X, Xb, Wv, Wt);
    gemm_bias<<<256, 512, 0, stream>>>(Xb, Wt, bv, out);
}

// Round 6
// 41.235 us; speedup vs baseline: 1.5099x; 1.4412x over previous
//
#include <hip/hip_runtime.h>
#include <hip/hip_bf16.h>

#define DIN  1024
#define DOUT 1024
#define MROWS 8192   // B*S = 4*2048

#define BM 128
#define BN 128
#define BK 64
#define NKT (DIN / BK)   // 16 K-tiles

typedef __attribute__((ext_vector_type(8))) short short8;
typedef __attribute__((ext_vector_type(4))) float f32x4;

__device__ __forceinline__ ushort f2bf(float f) {
    union { float f; unsigned u; } x; x.f = f;
    unsigned u = x.u + 0x7fffu + ((x.u >> 16) & 1u);  // RNE
    return (ushort)(u >> 16);
}

// ---------- pass 1 (fused): X f32->bf16 cvt  +  Wv [K][N] -> WvT [N][K] bf16 ----------
__global__ void prep_kernel(const float* __restrict__ X, ushort* __restrict__ Xb,
                            const float* __restrict__ W, ushort* __restrict__ Wt) {
    __shared__ float tile[32][33];
    const int b = blockIdx.x;
    if (b < 2048) {
        const float4* X4 = (const float4*)X;
        ushort4* O4 = (ushort4*)Xb;
        const int n4 = MROWS * DIN / 4;
        for (int idx = b * 256 + threadIdx.x; idx < n4; idx += 2048 * 256) {
            float4 v = X4[idx];
            ushort4 o;
            o.x = f2bf(v.x); o.y = f2bf(v.y); o.z = f2bf(v.z); o.w = f2bf(v.w);
            O4[idx] = o;
        }
    } else {
        const int t = b - 2048;            // 0..1023
        const int bx = (t & 31) * 32;      // n base
        const int by = (t >> 5) * 32;      // k base
        const int tx = threadIdx.x & 31;
        const int ty = threadIdx.x >> 5;   // 0..7
#pragma unroll
        for (int i = 0; i < 32; i += 8)
            tile[ty + i][tx] = W[(size_t)(by + ty + i) * DOUT + (bx + tx)];
        __syncthreads();
#pragma unroll
        for (int i = 0; i < 32; i += 8)
            Wt[(size_t)(bx + ty + i) * DIN + (by + tx)] = f2bf(tile[tx][ty + i]);
    }
}

// ---------- pass 2: C[M][N] = Xb[M][K] @ WvT[N][K]^T + bias ----------
// m97 structure: 128x128 tile, BK=64, 4 waves, double-buffered 64KB LDS ->
// 2 resident blocks/CU. Cross-block TLP hides the per-tile stage drain
// (m114/m97: implicit wave-level overlap beats source-level pipelining at
// multi-block occupancy). Stage via global_load_lds w16, source-XOR swizzle
// (rule #21), plain __syncthreads() per K-tile. No setprio (m190: null).
__global__ __launch_bounds__(256, 2) void gemm_bias(
    const ushort* __restrict__ Xb,    // [8192][1024] bf16
    const ushort* __restrict__ Wt,    // [1024 n][1024 k] bf16
    const float* __restrict__ bias,   // [1024]
    float* __restrict__ out)          // [8192][1024] f32
{
    __shared__ ushort As[2][BM * BK];   // 2 x 16 KiB
    __shared__ ushort Bs[2][BN * BK];   // 2 x 16 KiB   (64 KiB -> 2 blocks/CU)

    const int tid  = threadIdx.x;
    const int lane = tid & 63;
    const int wid  = tid >> 6;     // 0..3
    const int wr   = wid >> 1;     // 0..1  (wave M slab, 64 rows)
    const int wc   = wid & 1;      // 0..1  (wave N slab, 64 cols)

    // XCD-aware bijective swizzle: 512 blocks = 8 XCDs x 64.
    // Each XCD: 8 m-tiles x 8 n-tiles; n varies fastest -> one m-slab's
    // A panel (1MB eff.) is L2-hot across its 8 n-blocks.
    const int bid = blockIdx.x;
    const int swz = (bid & 7) * 64 + (bid >> 3);
    const int bm = (swz >> 3) * BM;
    const int bn = (swz & 7) * BN;

    // Stage K-tile kt into buffer b: 4+4 global_load_lds w16 per thread.
    // LDS dest LINEAR (wave-uniform base + lane*16); T2 swizzle applied by
    // XOR-permuting the global source 16B-chunk (both-sides involution).
    auto stage = [&](int b, int kt) {
#pragma unroll
        for (int i = 0; i < 4; ++i) {
            const int c   = i * 256 + tid;      // chunk 0..1023
            const int rl  = c >> 3;             // row 0..127
            const int scc = (c & 7) ^ (rl & 7); // swizzled source chunk
            __builtin_amdgcn_global_load_lds(
                (const __attribute__((address_space(1))) void*)(Xb + (size_t)(bm + rl) * DIN + kt * BK + scc * 8),
                (__attribute__((address_space(3))) void*)(&As[b][(i * 256 + wid * 64) * 8]),
                16, 0, 0);
        }
#pragma unroll
        for (int i = 0; i < 4; ++i) {
            const int c   = i * 256 + tid;
            const int rl  = c >> 3;
            const int scc = (c & 7) ^ (rl & 7);
            __builtin_amdgcn_global_load_lds(
                (const __attribute__((address_space(1))) void*)(Wt + (size_t)(bn + rl) * DIN + kt * BK + scc * 8),
                (__attribute__((address_space(3))) void*)(&Bs[b][(i * 256 + wid * 64) * 8]),
                16, 0, 0);
        }
    };

    f32x4 acc[4][4];
#pragma unroll
    for (int i = 0; i < 4; ++i)
#pragma unroll
        for (int j = 0; j < 4; ++j)
            acc[i][j] = (f32x4){0.f, 0.f, 0.f, 0.f};

    const int am  = wr * 64 + (lane & 15);
    const int bnr = wc * 64 + (lane & 15);

    // ---- prologue ----
    stage(0, 0);
    __syncthreads();

    // ---- main loop: issue stage(t+1) early, compute tile t, sync ----
    for (int t = 0; t < NKT; ++t) {
        const int buf = t & 1;
        if (t < NKT - 1) stage(buf ^ 1, t + 1);
#pragma unroll
        for (int ks = 0; ks < 2; ++ks) {
            short8 af[4], bfr[4];
            const int sc = ((ks * 4 + (lane >> 4)) ^ (lane & 7)) * 8;
#pragma unroll
            for (int i = 0; i < 4; ++i)
                af[i] = *(const short8*)(&As[buf][(am + i * 16) * BK + sc]);
#pragma unroll
            for (int j = 0; j < 4; ++j)
                bfr[j] = *(const short8*)(&Bs[buf][(bnr + j * 16) * BK + sc]);
#pragma unroll
            for (int i = 0; i < 4; ++i)
#pragma unroll
                for (int j = 0; j < 4; ++j)
                    acc[i][j] = __builtin_amdgcn_mfma_f32_16x16x32_bf16(af[i], bfr[j], acc[i][j], 0, 0, 0);
        }
        __syncthreads();
    }

    // ---- epilogue: bias + store. C/D: col = lane&15, row = (lane>>4)*4 + r ----
    const int crow = bm + wr * 64 + (lane >> 4) * 4;
    const int ccol = bn + wc * 64 + (lane & 15);
#pragma unroll
    for (int j = 0; j < 4; ++j) {
        const int col = ccol + j * 16;
        const float bval = bias[col];
#pragma unroll
        for (int i = 0; i < 4; ++i) {
#pragma unroll
            for (int r = 0; r < 4; ++r)
                out[(size_t)(crow + i * 16 + r) * DOUT + col] = acc[i][j][r] + bval;
        }
    }
}

// ---------- fallback (only if workspace too small): naive f32 ----------
__global__ void gemm_naive(const float* __restrict__ X, const float* __restrict__ W,
                           const float* __restrict__ b, float* __restrict__ out) {
    int n = blockIdx.x * blockDim.x + threadIdx.x;
    int m = blockIdx.y;
    float acc = b[n];
    for (int k = 0; k < DIN; ++k)
        acc += X[(size_t)m * DIN + k] * W[(size_t)k * DOUT + n];
    out[(size_t)m * DOUT + n] = acc;
}

extern "C" void kernel_launch(void* const* d_in, const int* in_sizes, int n_in,
                              void* d_out, int out_size, void* d_ws, size_t ws_size,
                              hipStream_t stream) {
    // setup_inputs order: X, Wq, bq, Wk, bk, Wv, bv
    const float* X  = (const float*)d_in[0];
    const float* Wv = (const float*)d_in[5];
    const float* bv = (const float*)d_in[6];
    float* out = (float*)d_out;

    const size_t xb_elems = (size_t)MROWS * DIN;
    const size_t wt_elems = (size_t)DOUT * DIN;
    const size_t needed = (xb_elems + wt_elems) * sizeof(ushort);

    if (ws_size < needed) {
        dim3 g(DOUT / 256, MROWS);
        gemm_naive<<<g, 256, 0, stream>>>(X, Wv, bv, out);
        return;
    }

    ushort* Xb = (ushort*)d_ws;
    ushort* Wt = Xb + xb_elems;

    prep_kernel<<<2048 + 1024, 256, 0, stream>>>(X, Xb, Wv, Wt);
    gemm_bias<<<512, 256, 0, stream>>>(Xb, Wt, bv, out);
}